// Round 4
// baseline (3226.679 us; speedup 1.0000x reference)
//
#include <hip/hip_runtime.h>
#include <hip/hip_bf16.h>
#include <cstdint>
#include <cstddef>

#define F_DIM 128
#define P_DIM 2048
#define RADIUS 4
#define HT_STRIDE 136   // ushorts per row: 272 B = 16B-aligned, 2-way bank alias only (free)
#define LOG2E 1.4426950408889634f

typedef short s16x8 __attribute__((ext_vector_type(8)));
typedef float f32x4 __attribute__((ext_vector_type(4)));

static __device__ __forceinline__ float bf2f(ushort u) {
    union { float f; uint i; } v; v.i = ((uint)u) << 16; return v.f;
}
static __device__ __forceinline__ ushort f2bf(float f) {
    uint u = __float_as_uint(f);
    uint r = (u + 0x7fffu + ((u >> 16) & 1u)) >> 16;   // RTN-even
    return (ushort)r;
}
static __device__ __forceinline__ f32x4 mfma16(s16x8 a, s16x8 b, f32x4 c) {
    return __builtin_amdgcn_mfma_f32_16x16x32_bf16(a, b, c, 0, 0, 0);
}

// ---------------- CSR build (once per launch) ----------------

__global__ void hist_kernel(const int* __restrict__ dst, int* __restrict__ counts, int E) {
    int e = blockIdx.x * blockDim.x + threadIdx.x;
    if (e < E) atomicAdd(&counts[dst[e]], 1);
}

__global__ __launch_bounds__(1024) void scan_kernel(const int* __restrict__ counts,
                                                    int* __restrict__ offs, int N) {
    __shared__ int buf[2][1024];
    __shared__ int carry_s;
    if (threadIdx.x == 0) carry_s = 0;
    __syncthreads();
    int nChunks = (N + 1023) >> 10;
    for (int c = 0; c < nChunks; ++c) {
        int i = (c << 10) + threadIdx.x;
        int v = (i < N) ? counts[i] : 0;
        int src = 0;
        buf[0][threadIdx.x] = v;
        __syncthreads();
        for (int off = 1; off < 1024; off <<= 1) {
            int d = src ^ 1;
            int val = buf[src][threadIdx.x];
            if (threadIdx.x >= (unsigned)off) val += buf[src][threadIdx.x - off];
            buf[d][threadIdx.x] = val;
            src = d;
            __syncthreads();
        }
        int inc = buf[src][threadIdx.x];
        if (i < N) offs[i + 1] = carry_s + inc;
        __syncthreads();
        if (threadIdx.x == 1023) carry_s += buf[src][1023];
        __syncthreads();
    }
    if (threadIdx.x == 0) offs[0] = 0;
}

__global__ void copy_kernel(const int* __restrict__ offs, int* __restrict__ cursor, int N) {
    int i = blockIdx.x * blockDim.x + threadIdx.x;
    if (i < N) cursor[i] = offs[i];
}

__global__ void scatter_kernel(const int* __restrict__ src, const int* __restrict__ dst,
                               int* __restrict__ cursor, int* __restrict__ srcs_sorted, int E) {
    int e = blockIdx.x * blockDim.x + threadIdx.x;
    if (e < E) {
        int d = dst[e];
        int pos = atomicAdd(&cursor[d], 1);
        srcs_sorted[pos] = src[e];
    }
}

// ---------------- one-time converts ----------------

__global__ void cvt_bf16_kernel(const float* __restrict__ src, ushort* __restrict__ dst, int n) {
    int i = blockIdx.x * blockDim.x + threadIdx.x;
    if (i < n) dst[i] = f2bf(src[i]);
}

__global__ void scale_kernel(const float* __restrict__ src, float* __restrict__ dst,
                             int n, float scale) {
    int i = blockIdx.x * blockDim.x + threadIdx.x;
    if (i < n) dst[i] = src[i] * scale;
}

// split fp32 W[K=128][P] (times scale) into hi+lo bf16, swizzled to MFMA B-frag order:
// dst[(((pt*4 + kt)*2 + s)*64 + lane)*8 + j] = split_s(scale*W[kt*32 + (lane>>4)*8 + j][pt*16 + (lane&15)])
__global__ void swizzle_split_kernel(const float* __restrict__ src, ushort* __restrict__ dst,
                                     int P, int total, float scale) {
    int d = blockIdx.x * blockDim.x + threadIdx.x;
    if (d >= total) return;
    int j    = d & 7;
    int lane = (d >> 3) & 63;
    int s    = (d >> 9) & 1;
    int kt   = (d >> 10) & 3;
    int pt   = d >> 12;
    int k = kt * 32 + (lane >> 4) * 8 + j;
    int p = pt * 16 + (lane & 15);
    float w = src[k * P + p] * scale;
    ushort hi = f2bf(w);
    ushort out = hi;
    if (s) out = f2bf(w - bf2f(hi));
    dst[d] = out;
}

// ---------------- aggregate (bf16 in, fp32 accum, bf16 out) ----------------
// one wave per node, uint (2×bf16) per lane

__global__ __launch_bounds__(256) void agg_kernel(const ushort* __restrict__ x,
                                                  const int* __restrict__ offs,
                                                  const int* __restrict__ srcs,
                                                  ushort* __restrict__ agg, int N) {
    int wid = (blockIdx.x * blockDim.x + threadIdx.x) >> 6;
    int lane = threadIdx.x & 63;
    if (wid >= N) return;
    const uint* xr = (const uint*)x;
    uint v = xr[(size_t)wid * 64 + lane];
    float a0 = bf2f((ushort)(v & 0xffffu));
    float a1 = bf2f((ushort)(v >> 16));
    int e0 = offs[wid], e1 = offs[wid + 1];
    for (int e = e0; e < e1; ++e) {
        uint u = xr[(size_t)srcs[e] * 64 + lane];
        a0 += bf2f((ushort)(u & 0xffffu));
        a1 += bf2f((ushort)(u >> 16));
    }
    ((uint*)agg)[(size_t)wid * 64 + lane] = ((uint)f2bf(a1) << 16) | (uint)f2bf(a0);
}

// ---------------- fused round ----------------
// block = 128 threads = 2 waves; 64 nodes/WAVE (4 groups of 16) -> 128 nodes/block.
// MFMA:B-load = 4:1. Softmax in exp2 domain (W2,b2 pre-scaled by log2e);
// pass1 = chunked online max/sum (1.5 exp per logit), pass2 normalization folded
// into the exponent: exp2(v + bb - m - log2 s).

__global__ __launch_bounds__(128, 2) void round_kernel(
        const ushort* __restrict__ agg,    // [N,128] bf16
        const ushort* __restrict__ w1sw,   // swizzled hi/lo bf16 (natural scale)
        const float*  __restrict__ b1,
        const ushort* __restrict__ w2sw,   // swizzled hi/lo bf16, scaled by log2e
        const float*  __restrict__ b2l,    // b2 * log2e
        ushort* __restrict__ h_out,        // [N,128] bf16 (next round x)
        float* __restrict__ fp,            // [2048]
        int N) {
    __shared__ ushort hT[128 * HT_STRIDE];  // 34.8 KB
    __shared__ float fp_s[P_DIM];           // 8 KB

    const int tid = threadIdx.x;
    const int w = tid >> 6;
    const int lane = tid & 63;
    const int q = lane >> 4;
    const int l15 = lane & 15;
    const int nodeBase = blockIdx.x * 128;
    const int wBase = w * 64;

    for (int i = tid; i < P_DIM; i += 128) fp_s[i] = 0.f;

    // ---- lin1: h = relu(agg @ W1 + b1) ----
    s16x8 a1[4][4];
    #pragma unroll
    for (int g = 0; g < 4; ++g) {
        int node = nodeBase + wBase + g * 16 + l15;
        #pragma unroll
        for (int kt = 0; kt < 4; ++kt) {
            if (node < N)
                a1[g][kt] = *(const s16x8*)(agg + (size_t)node * F_DIM + kt * 32 + q * 8);
            else
                a1[g][kt] = (s16x8){0, 0, 0, 0, 0, 0, 0, 0};
        }
    }
    for (int pt = 0; pt < 8; ++pt) {
        f32x4 c[4];
        #pragma unroll
        for (int g = 0; g < 4; ++g) c[g] = (f32x4){0.f, 0.f, 0.f, 0.f};
        #pragma unroll
        for (int kt = 0; kt < 4; ++kt) {
            s16x8 bh = *(const s16x8*)(w1sw + (size_t)(((pt * 4 + kt) * 2 + 0) * 64 + lane) * 8);
            s16x8 bl = *(const s16x8*)(w1sw + (size_t)(((pt * 4 + kt) * 2 + 1) * 64 + lane) * 8);
            #pragma unroll
            for (int g = 0; g < 4; ++g) {
                c[g] = mfma16(a1[g][kt], bh, c[g]);
                c[g] = mfma16(a1[g][kt], bl, c[g]);
            }
        }
        float bb = b1[pt * 16 + l15];
        #pragma unroll
        for (int g = 0; g < 4; ++g)
            #pragma unroll
            for (int r = 0; r < 4; ++r) {
                float v = c[g][r] + bb;
                v = v > 0.f ? v : 0.f;
                hT[(wBase + g * 16 + q * 4 + r) * HT_STRIDE + pt * 16 + l15] = f2bf(v);
            }
    }
    __syncthreads();

    // coalesced hT -> h_out: 128 rows x 16 chunks of 8 ushorts (ALL 128 columns)
    #pragma unroll
    for (int it = 0; it < 16; ++it) {
        int idx = it * 128 + tid;      // 0..2047
        int row = idx >> 4;            // 0..127
        int chunk = idx & 15;          // 0..15  (8 ushorts each = full 128 cols)
        int gnode = nodeBase + row;
        if (gnode < N) {
            s16x8 vv = *(const s16x8*)&hT[row * HT_STRIDE + chunk * 8];
            *(s16x8*)(h_out + (size_t)gnode * F_DIM + chunk * 8) = vv;
        }
    }

    // ---- lin2 A-frags from LDS ----
    s16x8 a2[4][4];
    #pragma unroll
    for (int g = 0; g < 4; ++g)
        #pragma unroll
        for (int kt = 0; kt < 4; ++kt)
            a2[g][kt] = *(const s16x8*)&hT[(wBase + g * 16 + l15) * HT_STRIDE + kt * 32 + q * 8];

    // ---- pass 1: chunked online max / sum-exp2 over 2048 logits ----
    float m_[4][4], s_[4][4];
    #pragma unroll
    for (int g = 0; g < 4; ++g)
        #pragma unroll
        for (int r = 0; r < 4; ++r) { m_[g][r] = -INFINITY; s_[g][r] = 0.f; }

    for (int ptb = 0; ptb < 64; ++ptb) {
        const int pt0 = ptb * 2;
        f32x4 c0[4], c1[4];
        #pragma unroll
        for (int g = 0; g < 4; ++g) {
            c0[g] = (f32x4){0.f, 0.f, 0.f, 0.f};
            c1[g] = (f32x4){0.f, 0.f, 0.f, 0.f};
        }
        #pragma unroll
        for (int kt = 0; kt < 4; ++kt) {
            s16x8 bh = *(const s16x8*)(w2sw + (size_t)(((pt0 * 4 + kt) * 2 + 0) * 64 + lane) * 8);
            s16x8 bl = *(const s16x8*)(w2sw + (size_t)(((pt0 * 4 + kt) * 2 + 1) * 64 + lane) * 8);
            #pragma unroll
            for (int g = 0; g < 4; ++g) {
                c0[g] = mfma16(a2[g][kt], bh, c0[g]);
                c0[g] = mfma16(a2[g][kt], bl, c0[g]);
            }
        }
        #pragma unroll
        for (int kt = 0; kt < 4; ++kt) {
            s16x8 bh = *(const s16x8*)(w2sw + (size_t)((((pt0 + 1) * 4 + kt) * 2 + 0) * 64 + lane) * 8);
            s16x8 bl = *(const s16x8*)(w2sw + (size_t)((((pt0 + 1) * 4 + kt) * 2 + 1) * 64 + lane) * 8);
            #pragma unroll
            for (int g = 0; g < 4; ++g) {
                c1[g] = mfma16(a2[g][kt], bh, c1[g]);
                c1[g] = mfma16(a2[g][kt], bl, c1[g]);
            }
        }
        float bb0 = b2l[pt0 * 16 + l15];
        float bb1 = b2l[pt0 * 16 + 16 + l15];
        #pragma unroll
        for (int g = 0; g < 4; ++g)
            #pragma unroll
            for (int r = 0; r < 4; ++r) {
                float v0 = c0[g][r] + bb0;
                float v1 = c1[g][r] + bb1;
                float cm = fmaxf(v0, v1);
                float nm = fmaxf(m_[g][r], cm);
                float s2 = exp2f(v0 - nm) + exp2f(v1 - nm);
                s_[g][r] = fmaf(s_[g][r], exp2f(m_[g][r] - nm), s2);
                m_[g][r] = nm;
            }
    }

    // merge (m,s) across the 16 p-lanes of each quad; fold normalization: bbk = -m - log2(s)
    float bbk[4][4];
    #pragma unroll
    for (int g = 0; g < 4; ++g)
        #pragma unroll
        for (int r = 0; r < 4; ++r) {
            float mm = m_[g][r], ss = s_[g][r];
            #pragma unroll
            for (int off = 1; off <= 8; off <<= 1) {
                float om = __shfl_xor(mm, off);
                float os = __shfl_xor(ss, off);
                float nm = fmaxf(mm, om);
                ss = ss * exp2f(mm - nm) + os * exp2f(om - nm);
                mm = nm;
            }
            int node = nodeBase + wBase + g * 16 + q * 4 + r;
            bbk[g][r] = (node < N) ? (-mm - __log2f(ss)) : -INFINITY;
        }

    // ---- pass 2: recompute logits, accumulate normalized probs ----
    for (int pt = 0; pt < 128; ++pt) {
        f32x4 c[4];
        #pragma unroll
        for (int g = 0; g < 4; ++g) c[g] = (f32x4){0.f, 0.f, 0.f, 0.f};
        #pragma unroll
        for (int kt = 0; kt < 4; ++kt) {
            s16x8 bh = *(const s16x8*)(w2sw + (size_t)(((pt * 4 + kt) * 2 + 0) * 64 + lane) * 8);
            s16x8 bl = *(const s16x8*)(w2sw + (size_t)(((pt * 4 + kt) * 2 + 1) * 64 + lane) * 8);
            #pragma unroll
            for (int g = 0; g < 4; ++g) {
                c[g] = mfma16(a2[g][kt], bh, c[g]);
                c[g] = mfma16(a2[g][kt], bl, c[g]);
            }
        }
        float bb = b2l[pt * 16 + l15];
        float tot = 0.f;
        #pragma unroll
        for (int g = 0; g < 4; ++g)
            #pragma unroll
            for (int r = 0; r < 4; ++r)
                tot += exp2f(c[g][r] + bb + bbk[g][r]);
        tot += __shfl_xor(tot, 16);
        tot += __shfl_xor(tot, 32);
        if (lane < 16) atomicAdd(&fp_s[pt * 16 + lane], tot);
    }
    __syncthreads();
    for (int i = tid; i < P_DIM; i += 128) atomicAdd(&fp[i], fp_s[i]);
}

// ---------------- launcher ----------------

extern "C" void kernel_launch(void* const* d_in, const int* in_sizes, int n_in,
                              void* d_out, int out_size, void* d_ws, size_t ws_size,
                              hipStream_t stream) {
    const float* atoms = (const float*)d_in[0];
    const float* W1    = (const float*)d_in[1];
    const float* b1    = (const float*)d_in[2];
    const float* W2    = (const float*)d_in[3];
    const float* b2    = (const float*)d_in[4];
    const int* esrc    = (const int*)d_in[5];
    const int* edst    = (const int*)d_in[6];
    float* fp          = (float*)d_out;
    const int N = in_sizes[0] / F_DIM;
    const int E = in_sizes[5];

    char* ws = (char*)d_ws;
    ushort* xA   = (ushort*)ws;  ws += (size_t)N * F_DIM * sizeof(ushort);
    ushort* xB   = (ushort*)ws;  ws += (size_t)N * F_DIM * sizeof(ushort);
    ushort* aggb = (ushort*)ws;  ws += (size_t)N * F_DIM * sizeof(ushort);
    ushort* w1sw = (ushort*)ws;  ws += (size_t)F_DIM * F_DIM * 2 * sizeof(ushort);
    ushort* w2sw = (ushort*)ws;  ws += (size_t)F_DIM * P_DIM * 2 * sizeof(ushort);
    float*  b2l  = (float*)ws;   ws += (size_t)P_DIM * sizeof(float);
    int* offs    = (int*)ws;     ws += (((size_t)(N + 1) * sizeof(int) + 255) & ~255ull);
    int* cursor  = (int*)ws;     ws += (((size_t)N * sizeof(int) + 255) & ~255ull);
    int* srcs    = (int*)ws;

    hipMemsetAsync(d_out, 0, (size_t)out_size * sizeof(float), stream);
    hipMemsetAsync(cursor, 0, (size_t)N * sizeof(int), stream);

    // CSR build
    int eb = (E + 255) / 256;
    hist_kernel<<<eb, 256, 0, stream>>>(edst, cursor, E);
    scan_kernel<<<1, 1024, 0, stream>>>(cursor, offs, N);
    copy_kernel<<<(N + 255) / 256, 256, 0, stream>>>(offs, cursor, N);
    scatter_kernel<<<eb, 256, 0, stream>>>(esrc, edst, cursor, srcs, E);

    // one-time converts
    int nconv = N * F_DIM;
    cvt_bf16_kernel<<<(nconv + 255) / 256, 256, 0, stream>>>(atoms, xA, nconv);
    int t1 = F_DIM * F_DIM * 2;
    swizzle_split_kernel<<<(t1 + 255) / 256, 256, 0, stream>>>(W1, w1sw, F_DIM, t1, 1.0f);
    int t2 = F_DIM * P_DIM * 2;
    swizzle_split_kernel<<<(t2 + 255) / 256, 256, 0, stream>>>(W2, w2sw, P_DIM, t2, LOG2E);
    scale_kernel<<<(P_DIM + 255) / 256, 256, 0, stream>>>(b2, b2l, P_DIM, LOG2E);

    const ushort* x = xA;
    ushort* xnext = xB;
    int rblocks = (N + 127) / 128;
    for (int r = 0; r < RADIUS; ++r) {
        agg_kernel<<<(N + 3) / 4, 256, 0, stream>>>(x, offs, srcs, aggb, N);
        round_kernel<<<rblocks, 128, 0, stream>>>(aggb, w1sw, b1, w2sw, b2l,
                                                  xnext, fp, N);
        x = xnext;
        xnext = (xnext == xB) ? xA : xB;
    }
}

// Round 5
// 2687.309 us; speedup vs baseline: 1.2007x; 1.2007x over previous
//
#include <hip/hip_runtime.h>
#include <hip/hip_bf16.h>
#include <cstdint>
#include <cstddef>

#define F_DIM 128
#define P_DIM 2048
#define RADIUS 4
#define HT_STRIDE 136   // ushorts per row: 272 B = 16B-aligned rows for b128 frag reads
#define LOG2E 1.4426950408889634f

typedef short s16x8 __attribute__((ext_vector_type(8)));
typedef float f32x4 __attribute__((ext_vector_type(4)));

static __device__ __forceinline__ float bf2f(ushort u) {
    union { float f; uint i; } v; v.i = ((uint)u) << 16; return v.f;
}
static __device__ __forceinline__ ushort f2bf(float f) {
    uint u = __float_as_uint(f);
    uint r = (u + 0x7fffu + ((u >> 16) & 1u)) >> 16;   // RTN-even
    return (ushort)r;
}
static __device__ __forceinline__ f32x4 mfma16(s16x8 a, s16x8 b, f32x4 c) {
    return __builtin_amdgcn_mfma_f32_16x16x32_bf16(a, b, c, 0, 0, 0);
}

// ---------------- CSR build (once per launch) ----------------

__global__ void hist_kernel(const int* __restrict__ dst, int* __restrict__ counts, int E) {
    int e = blockIdx.x * blockDim.x + threadIdx.x;
    if (e < E) atomicAdd(&counts[dst[e]], 1);
}

__global__ __launch_bounds__(1024) void scan_kernel(const int* __restrict__ counts,
                                                    int* __restrict__ offs, int N) {
    __shared__ int buf[2][1024];
    __shared__ int carry_s;
    if (threadIdx.x == 0) carry_s = 0;
    __syncthreads();
    int nChunks = (N + 1023) >> 10;
    for (int c = 0; c < nChunks; ++c) {
        int i = (c << 10) + threadIdx.x;
        int v = (i < N) ? counts[i] : 0;
        int src = 0;
        buf[0][threadIdx.x] = v;
        __syncthreads();
        for (int off = 1; off < 1024; off <<= 1) {
            int d = src ^ 1;
            int val = buf[src][threadIdx.x];
            if (threadIdx.x >= (unsigned)off) val += buf[src][threadIdx.x - off];
            buf[d][threadIdx.x] = val;
            src = d;
            __syncthreads();
        }
        int inc = buf[src][threadIdx.x];
        if (i < N) offs[i + 1] = carry_s + inc;
        __syncthreads();
        if (threadIdx.x == 1023) carry_s += buf[src][1023];
        __syncthreads();
    }
    if (threadIdx.x == 0) offs[0] = 0;
}

__global__ void copy_kernel(const int* __restrict__ offs, int* __restrict__ cursor, int N) {
    int i = blockIdx.x * blockDim.x + threadIdx.x;
    if (i < N) cursor[i] = offs[i];
}

__global__ void scatter_kernel(const int* __restrict__ src, const int* __restrict__ dst,
                               int* __restrict__ cursor, int* __restrict__ srcs_sorted, int E) {
    int e = blockIdx.x * blockDim.x + threadIdx.x;
    if (e < E) {
        int d = dst[e];
        int pos = atomicAdd(&cursor[d], 1);
        srcs_sorted[pos] = src[e];
    }
}

// ---------------- one-time converts ----------------

__global__ void cvt_bf16_kernel(const float* __restrict__ src, ushort* __restrict__ dst, int n) {
    int i = blockIdx.x * blockDim.x + threadIdx.x;
    if (i < n) dst[i] = f2bf(src[i]);
}

__global__ void scale_kernel(const float* __restrict__ src, float* __restrict__ dst,
                             int n, float scale) {
    int i = blockIdx.x * blockDim.x + threadIdx.x;
    if (i < n) dst[i] = src[i] * scale;
}

// split fp32 W[K=128][P] (times scale) into hi+lo bf16, swizzled to MFMA B-frag order:
// dst[(((pt*4 + kt)*2 + s)*64 + lane)*8 + j] = split_s(scale*W[kt*32 + (lane>>4)*8 + j][pt*16 + (lane&15)])
__global__ void swizzle_split_kernel(const float* __restrict__ src, ushort* __restrict__ dst,
                                     int P, int total, float scale) {
    int d = blockIdx.x * blockDim.x + threadIdx.x;
    if (d >= total) return;
    int j    = d & 7;
    int lane = (d >> 3) & 63;
    int s    = (d >> 9) & 1;
    int kt   = (d >> 10) & 3;
    int pt   = d >> 12;
    int k = kt * 32 + (lane >> 4) * 8 + j;
    int p = pt * 16 + (lane & 15);
    float w = src[k * P + p] * scale;
    ushort hi = f2bf(w);
    ushort out = hi;
    if (s) out = f2bf(w - bf2f(hi));
    dst[d] = out;
}

// ---------------- aggregate (bf16 in, fp32 accum, bf16 out) ----------------
// one wave per node, uint (2×bf16) per lane

__global__ __launch_bounds__(256) void agg_kernel(const ushort* __restrict__ x,
                                                  const int* __restrict__ offs,
                                                  const int* __restrict__ srcs,
                                                  ushort* __restrict__ agg, int N) {
    int wid = (blockIdx.x * blockDim.x + threadIdx.x) >> 6;
    int lane = threadIdx.x & 63;
    if (wid >= N) return;
    const uint* xr = (const uint*)x;
    uint v = xr[(size_t)wid * 64 + lane];
    float a0 = bf2f((ushort)(v & 0xffffu));
    float a1 = bf2f((ushort)(v >> 16));
    int e0 = offs[wid], e1 = offs[wid + 1];
    for (int e = e0; e < e1; ++e) {
        uint u = xr[(size_t)srcs[e] * 64 + lane];
        a0 += bf2f((ushort)(u & 0xffffu));
        a1 += bf2f((ushort)(u >> 16));
    }
    ((uint*)agg)[(size_t)wid * 64 + lane] = ((uint)f2bf(a1) << 16) | (uint)f2bf(a0);
}

// ---------------- fused round ----------------
// block = 64 threads = 1 wave owning 64 nodes (4 g-tiles of 16). Entirely wave-local:
// no __syncthreads anywhere (lin1->lin2 transpose via hT is same-wave, DS pipe in-order).
// B-fragments software-pipelined one pt ahead in registers to hide L2 latency under
// the 32-MFMA (~515 cyc) compute of the current pt. Softmax in exp2 domain.

__global__ __launch_bounds__(64, 2) void round_kernel(
        const ushort* __restrict__ agg,    // [N,128] bf16
        const ushort* __restrict__ w1sw,   // swizzled hi/lo bf16 (natural scale)
        const float*  __restrict__ b1,
        const ushort* __restrict__ w2sw,   // swizzled hi/lo bf16, scaled by log2e
        const float*  __restrict__ b2l,    // b2 * log2e
        ushort* __restrict__ h_out,        // [N,128] bf16 (next round x)
        float* __restrict__ fp,            // [2048]
        int N) {
    __shared__ ushort hT[64 * HT_STRIDE];  // 17.4 KB
    __shared__ float fp_s[P_DIM];          // 8 KB  -> 25.6 KB total, 6 blocks/CU

    const int lane = threadIdx.x;
    const int q = lane >> 4;
    const int l15 = lane & 15;
    const int nodeBase = blockIdx.x * 64;

    for (int i = lane; i < P_DIM; i += 64) fp_s[i] = 0.f;

    const s16x8* w1v = (const s16x8*)w1sw;   // frag index: (pt*8 + kt*2 + s)*64 + lane
    const s16x8* w2v = (const s16x8*)w2sw;

    // ---- lin1: h = relu(agg @ W1 + b1) ----
    s16x8 a[4][4];
    #pragma unroll
    for (int g = 0; g < 4; ++g) {
        int node = nodeBase + g * 16 + l15;
        #pragma unroll
        for (int kt = 0; kt < 4; ++kt) {
            if (node < N)
                a[g][kt] = *(const s16x8*)(agg + (size_t)node * F_DIM + kt * 32 + q * 8);
            else
                a[g][kt] = (s16x8){0, 0, 0, 0, 0, 0, 0, 0};
        }
    }
    #pragma unroll
    for (int pt = 0; pt < 8; ++pt) {
        f32x4 c[4];
        #pragma unroll
        for (int g = 0; g < 4; ++g) c[g] = (f32x4){0.f, 0.f, 0.f, 0.f};
        #pragma unroll
        for (int kt = 0; kt < 4; ++kt) {
            s16x8 bh = w1v[(size_t)(pt * 8 + kt * 2 + 0) * 64 + lane];
            s16x8 bl = w1v[(size_t)(pt * 8 + kt * 2 + 1) * 64 + lane];
            #pragma unroll
            for (int g = 0; g < 4; ++g) {
                c[g] = mfma16(a[g][kt], bh, c[g]);
                c[g] = mfma16(a[g][kt], bl, c[g]);
            }
        }
        float bb = b1[pt * 16 + l15];
        #pragma unroll
        for (int g = 0; g < 4; ++g)
            #pragma unroll
            for (int r = 0; r < 4; ++r) {
                float v = c[g][r] + bb;
                v = v > 0.f ? v : 0.f;
                hT[(g * 16 + q * 4 + r) * HT_STRIDE + pt * 16 + l15] = f2bf(v);
            }
    }

    // coalesced hT -> h_out: 64 rows x 16 chunks of 8 ushorts (all 128 cols)
    #pragma unroll
    for (int it = 0; it < 16; ++it) {
        int idx = it * 64 + lane;      // 0..1023
        int row = idx >> 4;            // 0..63
        int chunk = idx & 15;          // 0..15
        int gnode = nodeBase + row;
        if (gnode < N) {
            s16x8 vv = *(const s16x8*)&hT[row * HT_STRIDE + chunk * 8];
            *(s16x8*)(h_out + (size_t)gnode * F_DIM + chunk * 8) = vv;
        }
    }

    // ---- lin2 A-frags from hT (reuse a[][]) ----
    #pragma unroll
    for (int g = 0; g < 4; ++g)
        #pragma unroll
        for (int kt = 0; kt < 4; ++kt)
            a[g][kt] = *(const s16x8*)&hT[(g * 16 + l15) * HT_STRIDE + kt * 32 + q * 8];

    // ---- pass 1: online max / sum-exp2, B-frags pipelined one pt ahead ----
    float m_[16], s_[16];
    #pragma unroll
    for (int j = 0; j < 16; ++j) { m_[j] = -INFINITY; s_[j] = 0.f; }

    s16x8 bcur[8];
    #pragma unroll
    for (int f = 0; f < 8; ++f) bcur[f] = w2v[(size_t)f * 64 + lane];
    float bb = b2l[l15];

    for (int pt = 0; pt < 128; ++pt) {
        int ptn = (pt + 1) & 127;                  // wrap: harmless reload of pt 0
        s16x8 bnxt[8];
        #pragma unroll
        for (int f = 0; f < 8; ++f) bnxt[f] = w2v[(size_t)(ptn * 8 + f) * 64 + lane];
        float bbn = b2l[ptn * 16 + l15];

        f32x4 c[4];
        #pragma unroll
        for (int g = 0; g < 4; ++g) c[g] = (f32x4){0.f, 0.f, 0.f, 0.f};
        #pragma unroll
        for (int kt = 0; kt < 4; ++kt) {
            #pragma unroll
            for (int g = 0; g < 4; ++g) c[g] = mfma16(a[g][kt], bcur[kt * 2 + 0], c[g]);
            #pragma unroll
            for (int g = 0; g < 4; ++g) c[g] = mfma16(a[g][kt], bcur[kt * 2 + 1], c[g]);
        }
        #pragma unroll
        for (int g = 0; g < 4; ++g)
            #pragma unroll
            for (int r = 0; r < 4; ++r) {
                int j = g * 4 + r;
                float v = c[g][r] + bb;
                float nm = fmaxf(m_[j], v);
                s_[j] = fmaf(s_[j], exp2f(m_[j] - nm), exp2f(v - nm));
                m_[j] = nm;
            }
        #pragma unroll
        for (int f = 0; f < 8; ++f) bcur[f] = bnxt[f];
        bb = bbn;
    }

    // merge (m,s) across the 16 p-lanes of each quad; fold norm: bbk = -m - log2(s)
    float bbk[16];
    #pragma unroll
    for (int j = 0; j < 16; ++j) {
        float mm = m_[j], ss = s_[j];
        #pragma unroll
        for (int off = 1; off <= 8; off <<= 1) {
            float om = __shfl_xor(mm, off);
            float os = __shfl_xor(ss, off);
            float nm = fmaxf(mm, om);
            ss = ss * exp2f(mm - nm) + os * exp2f(om - nm);
            mm = nm;
        }
        int node = nodeBase + (j >> 2) * 16 + q * 4 + (j & 3);
        bbk[j] = (node < N) ? (-mm - __log2f(ss)) : -INFINITY;
    }

    // ---- pass 2: recompute logits, accumulate normalized probs ----
    #pragma unroll
    for (int f = 0; f < 8; ++f) bcur[f] = w2v[(size_t)f * 64 + lane];
    bb = b2l[l15];

    for (int pt = 0; pt < 128; ++pt) {
        int ptn = (pt + 1) & 127;
        s16x8 bnxt[8];
        #pragma unroll
        for (int f = 0; f < 8; ++f) bnxt[f] = w2v[(size_t)(ptn * 8 + f) * 64 + lane];
        float bbn = b2l[ptn * 16 + l15];

        f32x4 c[4];
        #pragma unroll
        for (int g = 0; g < 4; ++g) c[g] = (f32x4){0.f, 0.f, 0.f, 0.f};
        #pragma unroll
        for (int kt = 0; kt < 4; ++kt) {
            #pragma unroll
            for (int g = 0; g < 4; ++g) c[g] = mfma16(a[g][kt], bcur[kt * 2 + 0], c[g]);
            #pragma unroll
            for (int g = 0; g < 4; ++g) c[g] = mfma16(a[g][kt], bcur[kt * 2 + 1], c[g]);
        }
        float tot = 0.f;
        #pragma unroll
        for (int g = 0; g < 4; ++g)
            #pragma unroll
            for (int r = 0; r < 4; ++r)
                tot += exp2f(c[g][r] + bb + bbk[g * 4 + r]);
        tot += __shfl_xor(tot, 16);
        tot += __shfl_xor(tot, 32);
        if (lane < 16) atomicAdd(&fp_s[pt * 16 + lane], tot);
        #pragma unroll
        for (int f = 0; f < 8; ++f) bcur[f] = bnxt[f];
        bb = bbn;
    }

    for (int i = lane; i < P_DIM; i += 64) atomicAdd(&fp[i], fp_s[i]);
}

// ---------------- launcher ----------------

extern "C" void kernel_launch(void* const* d_in, const int* in_sizes, int n_in,
                              void* d_out, int out_size, void* d_ws, size_t ws_size,
                              hipStream_t stream) {
    const float* atoms = (const float*)d_in[0];
    const float* W1    = (const float*)d_in[1];
    const float* b1    = (const float*)d_in[2];
    const float* W2    = (const float*)d_in[3];
    const float* b2    = (const float*)d_in[4];
    const int* esrc    = (const int*)d_in[5];
    const int* edst    = (const int*)d_in[6];
    float* fp          = (float*)d_out;
    const int N = in_sizes[0] / F_DIM;
    const int E = in_sizes[5];

    char* ws = (char*)d_ws;
    ushort* xA   = (ushort*)ws;  ws += (size_t)N * F_DIM * sizeof(ushort);
    ushort* xB   = (ushort*)ws;  ws += (size_t)N * F_DIM * sizeof(ushort);
    ushort* aggb = (ushort*)ws;  ws += (size_t)N * F_DIM * sizeof(ushort);
    ushort* w1sw = (ushort*)ws;  ws += (size_t)F_DIM * F_DIM * 2 * sizeof(ushort);
    ushort* w2sw = (ushort*)ws;  ws += (size_t)F_DIM * P_DIM * 2 * sizeof(ushort);
    float*  b2l  = (float*)ws;   ws += (size_t)P_DIM * sizeof(float);
    int* offs    = (int*)ws;     ws += (((size_t)(N + 1) * sizeof(int) + 255) & ~255ull);
    int* cursor  = (int*)ws;     ws += (((size_t)N * sizeof(int) + 255) & ~255ull);
    int* srcs    = (int*)ws;

    hipMemsetAsync(d_out, 0, (size_t)out_size * sizeof(float), stream);
    hipMemsetAsync(cursor, 0, (size_t)N * sizeof(int), stream);

    // CSR build
    int eb = (E + 255) / 256;
    hist_kernel<<<eb, 256, 0, stream>>>(edst, cursor, E);
    scan_kernel<<<1, 1024, 0, stream>>>(cursor, offs, N);
    copy_kernel<<<(N + 255) / 256, 256, 0, stream>>>(offs, cursor, N);
    scatter_kernel<<<eb, 256, 0, stream>>>(esrc, edst, cursor, srcs, E);

    // one-time converts
    int nconv = N * F_DIM;
    cvt_bf16_kernel<<<(nconv + 255) / 256, 256, 0, stream>>>(atoms, xA, nconv);
    int t1 = F_DIM * F_DIM * 2;
    swizzle_split_kernel<<<(t1 + 255) / 256, 256, 0, stream>>>(W1, w1sw, F_DIM, t1, 1.0f);
    int t2 = F_DIM * P_DIM * 2;
    swizzle_split_kernel<<<(t2 + 255) / 256, 256, 0, stream>>>(W2, w2sw, P_DIM, t2, LOG2E);
    scale_kernel<<<(P_DIM + 255) / 256, 256, 0, stream>>>(b2, b2l, P_DIM, LOG2E);

    const ushort* x = xA;
    ushort* xnext = xB;
    int rblocks = (N + 63) / 64;
    for (int r = 0; r < RADIUS; ++r) {
        agg_kernel<<<(N + 3) / 4, 256, 0, stream>>>(x, offs, srcs, aggb, N);
        round_kernel<<<rblocks, 64, 0, stream>>>(aggb, w1sw, b1, w2sw, b2l,
                                                 xnext, fp, N);
        x = xnext;
        xnext = (xnext == xB) ? xA : xB;
    }
}

// Round 6
// 2541.261 us; speedup vs baseline: 1.2697x; 1.0575x over previous
//
#include <hip/hip_runtime.h>
#include <hip/hip_bf16.h>
#include <cstdint>
#include <cstddef>

#define F_DIM 128
#define P_DIM 2048
#define RADIUS 4
#define HT_STRIDE 136   // ushorts per row: 272 B = 16B-aligned rows for b128 frag reads
#define LOG2E 1.4426950408889634f

typedef short s16x8 __attribute__((ext_vector_type(8)));
typedef float f32x4 __attribute__((ext_vector_type(4)));

static __device__ __forceinline__ float bf2f(ushort u) {
    union { float f; uint i; } v; v.i = ((uint)u) << 16; return v.f;
}
static __device__ __forceinline__ ushort f2bf(float f) {
    uint u = __float_as_uint(f);
    uint r = (u + 0x7fffu + ((u >> 16) & 1u)) >> 16;   // RTN-even
    return (ushort)r;
}
static __device__ __forceinline__ f32x4 mfma16(s16x8 a, s16x8 b, f32x4 c) {
    return __builtin_amdgcn_mfma_f32_16x16x32_bf16(a, b, c, 0, 0, 0);
}

// ---------------- CSR build (once per launch) ----------------

__global__ void hist_kernel(const int* __restrict__ dst, int* __restrict__ counts, int E) {
    int e = blockIdx.x * blockDim.x + threadIdx.x;
    if (e < E) atomicAdd(&counts[dst[e]], 1);
}

__global__ __launch_bounds__(1024) void scan_kernel(const int* __restrict__ counts,
                                                    int* __restrict__ offs, int N) {
    __shared__ int buf[2][1024];
    __shared__ int carry_s;
    if (threadIdx.x == 0) carry_s = 0;
    __syncthreads();
    int nChunks = (N + 1023) >> 10;
    for (int c = 0; c < nChunks; ++c) {
        int i = (c << 10) + threadIdx.x;
        int v = (i < N) ? counts[i] : 0;
        int src = 0;
        buf[0][threadIdx.x] = v;
        __syncthreads();
        for (int off = 1; off < 1024; off <<= 1) {
            int d = src ^ 1;
            int val = buf[src][threadIdx.x];
            if (threadIdx.x >= (unsigned)off) val += buf[src][threadIdx.x - off];
            buf[d][threadIdx.x] = val;
            src = d;
            __syncthreads();
        }
        int inc = buf[src][threadIdx.x];
        if (i < N) offs[i + 1] = carry_s + inc;
        __syncthreads();
        if (threadIdx.x == 1023) carry_s += buf[src][1023];
        __syncthreads();
    }
    if (threadIdx.x == 0) offs[0] = 0;
}

__global__ void copy_kernel(const int* __restrict__ offs, int* __restrict__ cursor, int N) {
    int i = blockIdx.x * blockDim.x + threadIdx.x;
    if (i < N) cursor[i] = offs[i];
}

__global__ void scatter_kernel(const int* __restrict__ src, const int* __restrict__ dst,
                               int* __restrict__ cursor, int* __restrict__ srcs_sorted, int E) {
    int e = blockIdx.x * blockDim.x + threadIdx.x;
    if (e < E) {
        int d = dst[e];
        int pos = atomicAdd(&cursor[d], 1);
        srcs_sorted[pos] = src[e];
    }
}

// ---------------- one-time converts ----------------

__global__ void cvt_bf16_kernel(const float* __restrict__ src, ushort* __restrict__ dst, int n) {
    int i = blockIdx.x * blockDim.x + threadIdx.x;
    if (i < n) dst[i] = f2bf(src[i]);
}

__global__ void scale_kernel(const float* __restrict__ src, float* __restrict__ dst,
                             int n, float scale) {
    int i = blockIdx.x * blockDim.x + threadIdx.x;
    if (i < n) dst[i] = src[i] * scale;
}

// split fp32 W[K=128][P] (times scale) into hi+lo bf16, swizzled to MFMA B-frag order:
// dst[(((pt*4 + kt)*2 + s)*64 + lane)*8 + j] = split_s(scale*W[kt*32 + (lane>>4)*8 + j][pt*16 + (lane&15)])
__global__ void swizzle_split_kernel(const float* __restrict__ src, ushort* __restrict__ dst,
                                     int P, int total, float scale) {
    int d = blockIdx.x * blockDim.x + threadIdx.x;
    if (d >= total) return;
    int j    = d & 7;
    int lane = (d >> 3) & 63;
    int s    = (d >> 9) & 1;
    int kt   = (d >> 10) & 3;
    int pt   = d >> 12;
    int k = kt * 32 + (lane >> 4) * 8 + j;
    int p = pt * 16 + (lane & 15);
    float w = src[k * P + p] * scale;
    ushort hi = f2bf(w);
    ushort out = hi;
    if (s) out = f2bf(w - bf2f(hi));
    dst[d] = out;
}

// ---------------- aggregate (bf16 in, fp32 accum, bf16 out) ----------------
// one wave per node, uint (2×bf16) per lane

__global__ __launch_bounds__(256) void agg_kernel(const ushort* __restrict__ x,
                                                  const int* __restrict__ offs,
                                                  const int* __restrict__ srcs,
                                                  ushort* __restrict__ agg, int N) {
    int wid = (blockIdx.x * blockDim.x + threadIdx.x) >> 6;
    int lane = threadIdx.x & 63;
    if (wid >= N) return;
    const uint* xr = (const uint*)x;
    uint v = xr[(size_t)wid * 64 + lane];
    float a0 = bf2f((ushort)(v & 0xffffu));
    float a1 = bf2f((ushort)(v >> 16));
    int e0 = offs[wid], e1 = offs[wid + 1];
    for (int e = e0; e < e1; ++e) {
        uint u = xr[(size_t)srcs[e] * 64 + lane];
        a0 += bf2f((ushort)(u & 0xffffu));
        a1 += bf2f((ushort)(u >> 16));
    }
    ((uint*)agg)[(size_t)wid * 64 + lane] = ((uint)f2bf(a1) << 16) | (uint)f2bf(a0);
}

// ---------------- fused round ----------------
// block = 64 threads = 1 wave owning 64 nodes (4 g-tiles of 16). Entirely wave-local:
// no __syncthreads (DS pipe is in-order within a wave). LDS is a UNION: the hT
// transpose buffer (17.4 KB) is reused as fp_s (8 KB) once lin2 A-frags are in
// registers -> 9 blocks/CU instead of 6. B-fragments double-buffered with an
// explicit unroll-2 ping-pong (bA/bB) so the prefetch stays in registers.

__global__ __launch_bounds__(64, 2) void round_kernel(
        const ushort* __restrict__ agg,    // [N,128] bf16
        const ushort* __restrict__ w1sw,   // swizzled hi/lo bf16 (natural scale)
        const float*  __restrict__ b1,
        const ushort* __restrict__ w2sw,   // swizzled hi/lo bf16, scaled by log2e
        const float*  __restrict__ b2l,    // b2 * log2e
        ushort* __restrict__ h_out,        // [N,128] bf16 (next round x)
        float* __restrict__ fp,            // [2048]
        int N) {
    __shared__ ushort smem_u[64 * HT_STRIDE];  // 17.4 KB; hT first, fp_s after
    ushort* hT = smem_u;
    float* fp_s = (float*)smem_u;

    const int lane = threadIdx.x;
    const int q = lane >> 4;
    const int l15 = lane & 15;
    const int nodeBase = blockIdx.x * 64;

    const s16x8* w1v = (const s16x8*)w1sw;   // frag index: (pt*8 + kt*2 + s)*64 + lane
    const s16x8* w2v = (const s16x8*)w2sw;

    // ---- lin1: h = relu(agg @ W1 + b1) ----
    s16x8 a[4][4];
    #pragma unroll
    for (int g = 0; g < 4; ++g) {
        int node = nodeBase + g * 16 + l15;
        #pragma unroll
        for (int kt = 0; kt < 4; ++kt) {
            if (node < N)
                a[g][kt] = *(const s16x8*)(agg + (size_t)node * F_DIM + kt * 32 + q * 8);
            else
                a[g][kt] = (s16x8){0, 0, 0, 0, 0, 0, 0, 0};
        }
    }
    #pragma unroll
    for (int pt = 0; pt < 8; ++pt) {
        f32x4 c[4];
        #pragma unroll
        for (int g = 0; g < 4; ++g) c[g] = (f32x4){0.f, 0.f, 0.f, 0.f};
        #pragma unroll
        for (int kt = 0; kt < 4; ++kt) {
            s16x8 bh = w1v[(size_t)(pt * 8 + kt * 2 + 0) * 64 + lane];
            s16x8 bl = w1v[(size_t)(pt * 8 + kt * 2 + 1) * 64 + lane];
            #pragma unroll
            for (int g = 0; g < 4; ++g) {
                c[g] = mfma16(a[g][kt], bh, c[g]);
                c[g] = mfma16(a[g][kt], bl, c[g]);
            }
        }
        float bb = b1[pt * 16 + l15];
        #pragma unroll
        for (int g = 0; g < 4; ++g)
            #pragma unroll
            for (int r = 0; r < 4; ++r) {
                float v = c[g][r] + bb;
                v = v > 0.f ? v : 0.f;
                hT[(g * 16 + q * 4 + r) * HT_STRIDE + pt * 16 + l15] = f2bf(v);
            }
    }

    // coalesced hT -> h_out: 64 rows x 16 chunks of 8 ushorts (all 128 cols)
    #pragma unroll
    for (int it = 0; it < 16; ++it) {
        int idx = it * 64 + lane;      // 0..1023
        int row = idx >> 4;            // 0..63
        int chunk = idx & 15;          // 0..15
        int gnode = nodeBase + row;
        if (gnode < N) {
            s16x8 vv = *(const s16x8*)&hT[row * HT_STRIDE + chunk * 8];
            *(s16x8*)(h_out + (size_t)gnode * F_DIM + chunk * 8) = vv;
        }
    }

    // ---- lin2 A-frags from hT (reuse a[][]) ----
    #pragma unroll
    for (int g = 0; g < 4; ++g)
        #pragma unroll
        for (int kt = 0; kt < 4; ++kt)
            a[g][kt] = *(const s16x8*)&hT[(g * 16 + l15) * HT_STRIDE + kt * 32 + q * 8];

    // hT no longer needed: repurpose first 8 KB as fp_s (DS ops in-order per wave)
    for (int i = lane; i < P_DIM; i += 64) fp_s[i] = 0.f;

    // ---- pass 1: online max / sum-exp2, unroll-2 ping-pong B prefetch ----
    float m_[16], s_[16];
    #pragma unroll
    for (int j = 0; j < 16; ++j) { m_[j] = -INFINITY; s_[j] = 0.f; }

    s16x8 bA[8], bB[8];
    float bbA, bbB;
    #pragma unroll
    for (int f = 0; f < 8; ++f) bA[f] = w2v[(size_t)f * 64 + lane];
    bbA = b2l[l15];

    for (int pt = 0; pt < 128; pt += 2) {
        // prefetch pt+1
        #pragma unroll
        for (int f = 0; f < 8; ++f) bB[f] = w2v[(size_t)((pt + 1) * 8 + f) * 64 + lane];
        bbB = b2l[(pt + 1) * 16 + l15];
        {   // compute pt with bA
            f32x4 c[4];
            #pragma unroll
            for (int g = 0; g < 4; ++g) c[g] = (f32x4){0.f, 0.f, 0.f, 0.f};
            #pragma unroll
            for (int kt = 0; kt < 4; ++kt) {
                #pragma unroll
                for (int g = 0; g < 4; ++g) c[g] = mfma16(a[g][kt], bA[kt * 2 + 0], c[g]);
                #pragma unroll
                for (int g = 0; g < 4; ++g) c[g] = mfma16(a[g][kt], bA[kt * 2 + 1], c[g]);
            }
            #pragma unroll
            for (int g = 0; g < 4; ++g)
                #pragma unroll
                for (int r = 0; r < 4; ++r) {
                    int j = g * 4 + r;
                    float v = c[g][r] + bbA;
                    float nm = fmaxf(m_[j], v);
                    s_[j] = fmaf(s_[j], exp2f(m_[j] - nm), exp2f(v - nm));
                    m_[j] = nm;
                }
        }
        // prefetch pt+2 (wrap harmless)
        int pt2 = (pt + 2) & 127;
        #pragma unroll
        for (int f = 0; f < 8; ++f) bA[f] = w2v[(size_t)(pt2 * 8 + f) * 64 + lane];
        bbA = b2l[pt2 * 16 + l15];
        {   // compute pt+1 with bB
            f32x4 c[4];
            #pragma unroll
            for (int g = 0; g < 4; ++g) c[g] = (f32x4){0.f, 0.f, 0.f, 0.f};
            #pragma unroll
            for (int kt = 0; kt < 4; ++kt) {
                #pragma unroll
                for (int g = 0; g < 4; ++g) c[g] = mfma16(a[g][kt], bB[kt * 2 + 0], c[g]);
                #pragma unroll
                for (int g = 0; g < 4; ++g) c[g] = mfma16(a[g][kt], bB[kt * 2 + 1], c[g]);
            }
            #pragma unroll
            for (int g = 0; g < 4; ++g)
                #pragma unroll
                for (int r = 0; r < 4; ++r) {
                    int j = g * 4 + r;
                    float v = c[g][r] + bbB;
                    float nm = fmaxf(m_[j], v);
                    s_[j] = fmaf(s_[j], exp2f(m_[j] - nm), exp2f(v - nm));
                    m_[j] = nm;
                }
        }
    }

    // merge (m,s) across the 16 p-lanes of each quad; fold norm: bbk = -m - log2(s)
    float bbk[16];
    #pragma unroll
    for (int j = 0; j < 16; ++j) {
        float mm = m_[j], ss = s_[j];
        #pragma unroll
        for (int off = 1; off <= 8; off <<= 1) {
            float om = __shfl_xor(mm, off);
            float os = __shfl_xor(ss, off);
            float nm = fmaxf(mm, om);
            ss = ss * exp2f(mm - nm) + os * exp2f(om - nm);
            mm = nm;
        }
        int node = nodeBase + (j >> 2) * 16 + q * 4 + (j & 3);
        bbk[j] = (node < N) ? (-mm - __log2f(ss)) : -INFINITY;
    }

    // ---- pass 2: recompute logits, accumulate normalized probs ----
    #pragma unroll
    for (int f = 0; f < 8; ++f) bA[f] = w2v[(size_t)f * 64 + lane];
    bbA = b2l[l15];

    for (int pt = 0; pt < 128; pt += 2) {
        #pragma unroll
        for (int f = 0; f < 8; ++f) bB[f] = w2v[(size_t)((pt + 1) * 8 + f) * 64 + lane];
        bbB = b2l[(pt + 1) * 16 + l15];
        {   // compute pt with bA
            f32x4 c[4];
            #pragma unroll
            for (int g = 0; g < 4; ++g) c[g] = (f32x4){0.f, 0.f, 0.f, 0.f};
            #pragma unroll
            for (int kt = 0; kt < 4; ++kt) {
                #pragma unroll
                for (int g = 0; g < 4; ++g) c[g] = mfma16(a[g][kt], bA[kt * 2 + 0], c[g]);
                #pragma unroll
                for (int g = 0; g < 4; ++g) c[g] = mfma16(a[g][kt], bA[kt * 2 + 1], c[g]);
            }
            float tot = 0.f;
            #pragma unroll
            for (int g = 0; g < 4; ++g)
                #pragma unroll
                for (int r = 0; r < 4; ++r)
                    tot += exp2f(c[g][r] + bbA + bbk[g * 4 + r]);
            tot += __shfl_xor(tot, 16);
            tot += __shfl_xor(tot, 32);
            if (lane < 16) atomicAdd(&fp_s[pt * 16 + lane], tot);
        }
        int pt2 = (pt + 2) & 127;
        #pragma unroll
        for (int f = 0; f < 8; ++f) bA[f] = w2v[(size_t)(pt2 * 8 + f) * 64 + lane];
        bbA = b2l[pt2 * 16 + l15];
        {   // compute pt+1 with bB
            f32x4 c[4];
            #pragma unroll
            for (int g = 0; g < 4; ++g) c[g] = (f32x4){0.f, 0.f, 0.f, 0.f};
            #pragma unroll
            for (int kt = 0; kt < 4; ++kt) {
                #pragma unroll
                for (int g = 0; g < 4; ++g) c[g] = mfma16(a[g][kt], bB[kt * 2 + 0], c[g]);
                #pragma unroll
                for (int g = 0; g < 4; ++g) c[g] = mfma16(a[g][kt], bB[kt * 2 + 1], c[g]);
            }
            float tot = 0.f;
            #pragma unroll
            for (int g = 0; g < 4; ++g)
                #pragma unroll
                for (int r = 0; r < 4; ++r)
                    tot += exp2f(c[g][r] + bbB + bbk[g * 4 + r]);
            tot += __shfl_xor(tot, 16);
            tot += __shfl_xor(tot, 32);
            if (lane < 16) atomicAdd(&fp_s[(pt + 1) * 16 + lane], tot);
        }
    }

    for (int i = lane; i < P_DIM; i += 64) atomicAdd(&fp[i], fp_s[i]);
}

// ---------------- launcher ----------------

extern "C" void kernel_launch(void* const* d_in, const int* in_sizes, int n_in,
                              void* d_out, int out_size, void* d_ws, size_t ws_size,
                              hipStream_t stream) {
    const float* atoms = (const float*)d_in[0];
    const float* W1    = (const float*)d_in[1];
    const float* b1    = (const float*)d_in[2];
    const float* W2    = (const float*)d_in[3];
    const float* b2    = (const float*)d_in[4];
    const int* esrc    = (const int*)d_in[5];
    const int* edst    = (const int*)d_in[6];
    float* fp          = (float*)d_out;
    const int N = in_sizes[0] / F_DIM;
    const int E = in_sizes[5];

    char* ws = (char*)d_ws;
    ushort* xA   = (ushort*)ws;  ws += (size_t)N * F_DIM * sizeof(ushort);
    ushort* xB   = (ushort*)ws;  ws += (size_t)N * F_DIM * sizeof(ushort);
    ushort* aggb = (ushort*)ws;  ws += (size_t)N * F_DIM * sizeof(ushort);
    ushort* w1sw = (ushort*)ws;  ws += (size_t)F_DIM * F_DIM * 2 * sizeof(ushort);
    ushort* w2sw = (ushort*)ws;  ws += (size_t)F_DIM * P_DIM * 2 * sizeof(ushort);
    float*  b2l  = (float*)ws;   ws += (size_t)P_DIM * sizeof(float);
    int* offs    = (int*)ws;     ws += (((size_t)(N + 1) * sizeof(int) + 255) & ~255ull);
    int* cursor  = (int*)ws;     ws += (((size_t)N * sizeof(int) + 255) & ~255ull);
    int* srcs    = (int*)ws;

    hipMemsetAsync(d_out, 0, (size_t)out_size * sizeof(float), stream);
    hipMemsetAsync(cursor, 0, (size_t)N * sizeof(int), stream);

    // CSR build
    int eb = (E + 255) / 256;
    hist_kernel<<<eb, 256, 0, stream>>>(edst, cursor, E);
    scan_kernel<<<1, 1024, 0, stream>>>(cursor, offs, N);
    copy_kernel<<<(N + 255) / 256, 256, 0, stream>>>(offs, cursor, N);
    scatter_kernel<<<eb, 256, 0, stream>>>(esrc, edst, cursor, srcs, E);

    // one-time converts
    int nconv = N * F_DIM;
    cvt_bf16_kernel<<<(nconv + 255) / 256, 256, 0, stream>>>(atoms, xA, nconv);
    int t1 = F_DIM * F_DIM * 2;
    swizzle_split_kernel<<<(t1 + 255) / 256, 256, 0, stream>>>(W1, w1sw, F_DIM, t1, 1.0f);
    int t2 = F_DIM * P_DIM * 2;
    swizzle_split_kernel<<<(t2 + 255) / 256, 256, 0, stream>>>(W2, w2sw, P_DIM, t2, LOG2E);
    scale_kernel<<<(P_DIM + 255) / 256, 256, 0, stream>>>(b2, b2l, P_DIM, LOG2E);

    const ushort* x = xA;
    ushort* xnext = xB;
    int rblocks = (N + 63) / 64;
    for (int r = 0; r < RADIUS; ++r) {
        agg_kernel<<<(N + 3) / 4, 256, 0, stream>>>(x, offs, srcs, aggb, N);
        round_kernel<<<rblocks, 64, 0, stream>>>(aggb, w1sw, b1, w2sw, b2l,
                                                 xnext, fp, N);
        x = xnext;
        xnext = (xnext == xB) ? xA : xB;
    }
}